// Round 8
// baseline (117.957 us; speedup 1.0000x reference)
//
#include <hip/hip_runtime.h>
#include <math.h>

// SIDIS forward, round 8: round-7 flavor-contraction table + counting-sort of
// events by table bucket (ip_rel*NKF+kf_rel) for L2/L1 locality, with XCD
// swizzle so each XCD's concurrent window is a contiguous sorted range.
// Pipeline: zero_hist -> prep_all(+hist) -> build_htab -> scan -> scatter -> main.

namespace {
constexpr int   kNB    = 256;
constexpr int   kNX    = 256;
constexpr float kLXMIN = -9.210340371976182f;   // log(1e-4)
constexpr float kLBMIN = -6.907755278982137f;   // log(1e-3)
constexpr float kLBMAX =  3.912023005428146f;   // log(50)
constexpr float kScaleB = (float)(kNB - 1) / (kLBMAX - kLBMIN);
constexpr float kScaleX = (float)(kNX - 1) / (0.0f - kLXMIN);
constexpr float kG2    = 0.12f;
constexpr float kM2    = 0.8803f;
constexpr float kSmM2  = 140.0f - 0.8803f;      // S_MAND - M2
constexpr float kALPHA0 = 1.0f / 137.035999f;
constexpr float kLogME2 = -14.858672703081717f; // log(0.000511^2)
constexpr float kLog2E  = 1.4426950408889634f;
constexpr int   kGridElems = kNX * kNB;          // 65536 cells per flavor

constexpr int IP0 = 128, NIP = 120;   // pdf x-rows 128..247 (need 131..244)
constexpr int KF0 = 207, NKF = 46;    // ff  z-rows 207..252 (need 210..250)
constexpr int kPlaneStrideB = 256 * 8;           // bytes per (ip,kf) j-plane
constexpr int NBUCK = NIP * NKF;                 // 5520
constexpr int NBUCK_PAD = 5632;                  // 22*256
constexpr int SEG = 22;                          // scan items per thread
}

typedef float    f32x4 __attribute__((ext_vector_type(4)));
typedef _Float16 f16x8 __attribute__((ext_vector_type(8)));
typedef _Float16 f16x4 __attribute__((ext_vector_type(4)));

__device__ __forceinline__ float frcp(float x) { return __builtin_amdgcn_rcpf(x); }

#if __has_builtin(__builtin_amdgcn_exp2f)
__device__ __forceinline__ float fexp2(float x) { return __builtin_amdgcn_exp2f(x); }
#else
__device__ __forceinline__ float fexp2(float x) { return __expf(x * 0.6931471805599453f); }
#endif

// ---- zero the bucket histogram (must precede prep_all's atomics) ----
__global__ __launch_bounds__(256) void zero_hist(int* __restrict__ hist)
{
    for (int i = threadIdx.x; i < NBUCK_PAD; i += 256) hist[i] = 0;
}

// ---- prep: repack grids (E2 into pdf) + event consts + node consts + hist
// evc[ev] = { fbofs, nD2, scale, w00 | w01, w10, w11, bits(baseByte) }
__global__ __launch_bounds__(256) void prep_all(
    const float* __restrict__ pdfg, const float* __restrict__ ffg,
    const float* __restrict__ events,
    const float* __restrict__ ogx, const float* __restrict__ ogw,
    const float* __restrict__ fnp,
    _Float16* __restrict__ wpdf, _Float16* __restrict__ wff,
    float* __restrict__ evc, float* __restrict__ knode,
    int* __restrict__ hist)
{
    const int idx = blockIdx.x * 256 + threadIdx.x;   // cell idx == event idx

    // (a) flavor-innermost f16 repack, E2 folded into pdf
    const float E2a[8] = {4.f/9, 1.f/9, 1.f/9, 4.f/9, 4.f/9, 1.f/9, 1.f/9, 4.f/9};
    f16x8 p, q;
    #pragma unroll
    for (int f = 0; f < 8; ++f) {
        p[f] = (_Float16)(pdfg[f * kGridElems + idx] * E2a[f]);
        q[f] = (_Float16)ffg[f * kGridElems + idx];
    }
    reinterpret_cast<f16x8*>(wpdf)[idx] = p;
    reinterpret_cast<f16x8*>(wff )[idx] = q;

    // (b) node constants
    if (blockIdx.x == 0 && threadIdx.x < 64) {
        const float u = ogx[threadIdx.x];
        reinterpret_cast<f32x4*>(knode)[threadIdx.x] =
            (f32x4){__logf(u) * kScaleB, ogw[threadIdx.x], u * u, 0.0f};
    }

    // (c) per-event constants
    const float4 e = reinterpret_cast<const float4*>(events)[idx];
    const float x = e.x, PhT = e.y, Q = e.z, z = e.w;

    const float lam_p = log1pf(__expf(fnp[0]));
    const float lam_f = log1pf(__expf(fnp[1]));
    const float sig2  = frcp(1.0f + __expf(-fnp[2]));
    const float sig3  = frcp(1.0f + __expf(-fnp[3]));

    const float rz  = frcp(z);
    const float qT  = PhT * rz;
    const float rqT = z * frcp(PhT);
    const float Q2  = Q * Q;
    const float lx  = __logf(x);
    const float lz  = __logf(z);
    const float lqT = __logf(qT);
    const float lQ2 = 2.0f * __logf(Q);

    const float fbofs = (-lqT - kLBMIN) * kScaleB;

    float fxp = (lx - kLXMIN) * kScaleX;
    fxp = fminf(fmaxf(fxp, 0.0f), (float)(kNX - 1) - 1e-4f);
    const int   i0p = (int)fxp;
    const float txp = fxp - (float)i0p;

    float fxf = (lz - kLXMIN) * kScaleX;
    fxf = fminf(fmaxf(fxf, 0.0f), (float)(kNX - 1) - 1e-4f);
    const int   i0f = (int)fxf;
    const float txf = fxf - (float)i0f;

    const float D  = kG2 * lQ2
                   + lam_p * (1.0f - sig2 * lx)
                   + lam_f * (1.0f + sig3) * (rz * rz);
    const float nD2 = -(rqT * rqT) * D * kLog2E;     // exp2-ready

    const float alpha = kALPHA0 *
        frcp(1.0f - kALPHA0 / (3.0f * (float)M_PI) * (lQ2 - kLogME2));
    const float rQ    = frcp(Q);
    const float rx    = frcp(x);
    const float gamma = 2.0f * kM2 * x * rQ;
    const float y     = Q2 * rx * (1.0f / kSmM2);
    const float g2y2  = 0.25f * gamma * gamma * y * y;
    const float eps   = (1.0f - y - g2y2) *
                        frcp(1.0f - y + 0.5f * y * y + g2y2);
    const float pre   = 8.0f * (float)(M_PI * M_PI) * alpha * alpha
                      * z * z * qT * rx * (rQ * rQ * rQ)
                      * y * y * 0.5f * frcp(1.0f - eps)
                      * fmaf(gamma * gamma * 0.5f, rx, 1.0f);
    const float scale = pre * rqT * rqT;

    const int ip_rel = min(max(i0p - IP0, 0), NIP - 2);
    const int kf_rel = min(max(i0f - KF0, 0), NKF - 2);
    const float w00 = (1.0f - txp) * (1.0f - txf);
    const float w01 = (1.0f - txp) * txf;
    const float w10 = txp * (1.0f - txf);
    const float w11 = txp * txf;
    const int bucket = ip_rel * NKF + kf_rel;
    const int baseByte = bucket * kPlaneStrideB;

    f32x4* dst = reinterpret_cast<f32x4*>(evc + (size_t)idx * 8);
    dst[0] = (f32x4){fbofs, nD2, scale, w00};
    dst[1] = (f32x4){w01, w10, w11, __int_as_float(baseByte)};

    atomicAdd(&hist[bucket], 1);
}

// ---- build the flavor-contraction table ----
// htab[((ip_rel*NKF + kf_rel)*256 + j)] = f16x4{H00, H01+H10, H11, 0}
__global__ __launch_bounds__(256) void build_htab(
    const _Float16* __restrict__ wpdf,
    const _Float16* __restrict__ wff,
    _Float16* __restrict__ htab)
{
    const int kf_rel = blockIdx.x;        // 0..NKF-1
    const int ip_rel = blockIdx.y;        // 0..NIP-1
    const int j  = threadIdx.x;
    const int j1 = min(j + 1, 255);

    const int iprow = (IP0 + ip_rel) * kNB;
    const int kfrow = (KF0 + kf_rel) * kNB;

    const f16x8 p0 = reinterpret_cast<const f16x8*>(wpdf)[iprow + j];
    const f16x8 p1 = reinterpret_cast<const f16x8*>(wpdf)[iprow + j1];
    const f16x8 q0 = reinterpret_cast<const f16x8*>(wff )[kfrow + j];
    const f16x8 q1 = reinterpret_cast<const f16x8*>(wff )[kfrow + j1];

    float h00 = 0.f, h01 = 0.f, h10 = 0.f, h11 = 0.f;
    #pragma unroll
    for (int f = 0; f < 8; ++f) {
        const float a0 = (float)p0[f], a1 = (float)p1[f];
        const float b0 = (float)q0[f], b1 = (float)q1[f];
        h00 = fmaf(a0, b0, h00);
        h01 = fmaf(a0, b1, h01);
        h10 = fmaf(a1, b0, h10);
        h11 = fmaf(a1, b1, h11);
    }

    const int cell = (ip_rel * NKF + kf_rel) * 256 + j;
    reinterpret_cast<f16x4*>(htab)[cell] =
        (f16x4){(_Float16)h00, (_Float16)(h01 + h10), (_Float16)h11, (_Float16)0.f};
}

// ---- exclusive prefix sum of hist -> offs (one block) ----
__global__ __launch_bounds__(256) void scan_hist(
    const int* __restrict__ hist, int* __restrict__ offs)
{
    __shared__ int partial[256];
    const int t = threadIdx.x;
    const int base = t * SEG;
    int loc[SEG];
    int sum = 0;
    #pragma unroll
    for (int i = 0; i < SEG; ++i) {
        const int idx = base + i;
        const int v = (idx < NBUCK) ? hist[idx] : 0;
        loc[i] = sum;
        sum += v;
    }
    partial[t] = sum;
    __syncthreads();
    // Hillis-Steele inclusive scan over 256 partials
    #pragma unroll
    for (int d = 1; d < 256; d <<= 1) {
        int v = (t >= d) ? partial[t - d] : 0;
        __syncthreads();
        partial[t] += v;
        __syncthreads();
    }
    const int excl = (t == 0) ? 0 : partial[t - 1];
    #pragma unroll
    for (int i = 0; i < SEG; ++i) {
        const int idx = base + i;
        if (idx < NBUCK) offs[idx] = excl + loc[i];
    }
}

// ---- scatter: perm[sorted position] = event id ----
__global__ __launch_bounds__(256) void scatter_perm(
    const float* __restrict__ evc, int* __restrict__ offs,
    int* __restrict__ perm)
{
    const int ev = blockIdx.x * 256 + threadIdx.x;
    const int baseByte = __float_as_int(evc[(size_t)ev * 8 + 7]);
    const int bucket = baseByte >> 11;           // / kPlaneStrideB
    const int pos = atomicAdd(&offs[bucket], 1);
    perm[pos] = ev;
}

// ---- main: one wave per SORTED event; XCD-swizzled block order ----
__global__ __launch_bounds__(256) void sidis_fwd8(
    const float* __restrict__ evc,
    const _Float16* __restrict__ htab,
    const float* __restrict__ knode,
    const int* __restrict__ perm,
    float* __restrict__ out)
{
    const int lane = threadIdx.x & 63;
    const int wslt = threadIdx.x >> 6;

    // XCD swizzle: round-robin blockIdx%8 -> contiguous sorted chunks per XCD
    const int chunk = (int)(gridDim.x >> 3);
    const int sb = (blockIdx.x & 7) * chunk + (blockIdx.x >> 3);
    const int spos = (sb << 2) + wslt;

    const int ev = __builtin_amdgcn_readfirstlane(perm[spos]);

    const f32x4 c1 = reinterpret_cast<const f32x4*>(evc)[ev * 2];
    const f32x4 c2 = reinterpret_cast<const f32x4*>(evc)[ev * 2 + 1];
    const f32x4 kn = reinterpret_cast<const f32x4*>(knode)[lane];

    const float fbofs = c1.x, nD2 = c1.y, scale = c1.z;
    const _Float16 w00h = (_Float16)c1.w;
    const _Float16 w01h = (_Float16)c2.x;
    const _Float16 w10h = (_Float16)c2.y;
    const _Float16 w11h = (_Float16)c2.z;
    const int baseByte = __builtin_amdgcn_readfirstlane(__float_as_int(c2.w));

    float fb = kn.x + fbofs;
    fb = fminf(fmaxf(fb, 0.0f), (float)(kNB - 1) - 1e-4f);
    const int j0 = (int)fb;
    const float tb = fb - (float)j0;

    const char* t0 = reinterpret_cast<const char*>(htab) + baseByte + (j0 << 3);
    const char* t1 = t0 + (size_t)NKF * kPlaneStrideB;     // ip_rel+1 planes

    const f16x4 c00 = *reinterpret_cast<const f16x4*>(t0);
    const f16x4 c01 = *reinterpret_cast<const f16x4*>(t0 + kPlaneStrideB);
    const f16x4 c10 = *reinterpret_cast<const f16x4*>(t1);
    const f16x4 c11 = *reinterpret_cast<const f16x4*>(t1 + kPlaneStrideB);

    const f16x4 hc = w00h * c00 + w01h * c01 + w10h * c10 + w11h * c11;

    const float omtb = 1.0f - tb;
    const float s = omtb * omtb * (float)hc[0]
                  + omtb * tb   * (float)hc[1]
                  + tb   * tb   * (float)hc[2];

    float val = s * fexp2(kn.z * nD2) * kn.y;

    #pragma unroll
    for (int off = 32; off > 0; off >>= 1)
        val += __shfl_down(val, off, 64);

    if (lane == 0)
        out[ev] = scale * val;
}

// ---- fallback (ws too small): direct kernel ----
__global__ __launch_bounds__(256) void sidis_fwd_direct(
    const float* __restrict__ events,
    const float* __restrict__ pdfg,
    const float* __restrict__ ffg,
    const float* __restrict__ ogx,
    const float* __restrict__ ogw,
    const float* __restrict__ fnp,
    float* __restrict__ out)
{
    const int lane = threadIdx.x & 63;
    const int ev   = (blockIdx.x << 2) + (threadIdx.x >> 6);

    const float4 e = reinterpret_cast<const float4*>(events)[ev];
    const float x = e.x, PhT = e.y, Q = e.z, z = e.w;
    const float qT = PhT / z;
    const float Q2 = Q * Q;

    const float lam_p = log1pf(__expf(fnp[0]));
    const float lam_f = log1pf(__expf(fnp[1]));
    const float sig2  = 1.0f / (1.0f + __expf(-fnp[2]));
    const float sig3  = 1.0f / (1.0f + __expf(-fnp[3]));

    const float u_k = ogx[lane];
    const float w_k = ogw[lane];
    const float bT  = u_k / qT;
    const float lb  = __logf(bT);

    float fb = (lb - kLBMIN) * kScaleB;
    fb = fminf(fmaxf(fb, 0.0f), (float)(kNB - 1) - 1e-4f);
    const int   j0 = (int)fb;
    const float tb = fb - (float)j0;

    const float lx = __logf(x);
    float fxp = (lx - kLXMIN) * kScaleX;
    fxp = fminf(fmaxf(fxp, 0.0f), (float)(kNX - 1) - 1e-4f);
    const int   i0p = (int)fxp;
    const float txp = fxp - (float)i0p;

    const float lz = __logf(z);
    float fxf = (lz - kLXMIN) * kScaleX;
    fxf = fminf(fmaxf(fxf, 0.0f), (float)(kNX - 1) - 1e-4f);
    const int   i0f = (int)fxf;
    const float txf = fxf - (float)i0f;

    const float* pbase = pdfg + i0p * kNB + j0;
    const float* fbase = ffg  + i0f * kNB + j0;
    const float E2a[8] = {4.f/9, 1.f/9, 1.f/9, 4.f/9, 4.f/9, 1.f/9, 1.f/9, 4.f/9};

    float s = 0.0f;
    #pragma unroll
    for (int f = 0; f < 8; ++f) {
        const float* gp = pbase + f * kGridElems;
        const float p00 = gp[0], p01 = gp[1], p10 = gp[kNB], p11 = gp[kNB + 1];
        const float* gf = fbase + f * kGridElems;
        const float q00 = gf[0], q01 = gf[1], q10 = gf[kNB], q11 = gf[kNB + 1];
        const float pv = (1.0f - txp) * ((1.0f - tb) * p00 + tb * p01)
                       +          txp * ((1.0f - tb) * p10 + tb * p11);
        const float fv = (1.0f - txf) * ((1.0f - tb) * q00 + tb * q01)
                       +          txf * ((1.0f - tb) * q10 + tb * q11);
        s += E2a[f] * pv * fv;
    }

    const float bT2 = bT * bT;
    const float lQ2 = __logf(Q2);
    const float expo = -bT2 * (kG2 * lQ2
                               + lam_p * (1.0f - sig2 * lx)
                               + lam_f * (1.0f + sig3) / (z * z));
    float val = s * __expf(expo) * w_k;

    #pragma unroll
    for (int off = 32; off > 0; off >>= 1)
        val += __shfl_down(val, off, 64);

    if (lane == 0) {
        const float FUUT  = val / (qT * qT);
        const float alpha = kALPHA0 /
            (1.0f - kALPHA0 / (3.0f * (float)M_PI) * (lQ2 - kLogME2));
        const float gamma = 2.0f * kM2 * x / Q;
        const float y     = Q2 / (x * kSmM2);
        const float g2y2  = 0.25f * gamma * gamma * y * y;
        const float eps   = (1.0f - y - g2y2) /
                            (1.0f - y + 0.5f * y * y + g2y2);
        const float pre   = 8.0f * (float)(M_PI * M_PI) * alpha * alpha
                          * z * z * qT / x / (Q2 * Q)
                          * y * y * 0.5f / (1.0f - eps)
                          * (1.0f + gamma * gamma / (2.0f * x));
        out[ev] = pre * FUUT;
    }
}

extern "C" void kernel_launch(void* const* d_in, const int* in_sizes, int n_in,
                              void* d_out, int out_size, void* d_ws, size_t ws_size,
                              hipStream_t stream) {
    const float* events = (const float*)d_in[0];   // (65536, 4)
    const float* pdfg   = (const float*)d_in[1];   // (8, 256, 256)
    const float* ffg    = (const float*)d_in[2];   // (8, 256, 256)
    const float* ogx    = (const float*)d_in[3];   // (64,)
    const float* ogw    = (const float*)d_in[4];   // (64,)
    const float* fnp    = (const float*)d_in[5];   // (4,)
    float* out = (float*)d_out;

    const int nev = in_sizes[0] / 4;               // 65536

    // ws: wpdf 1MB | wff 1MB | evc 2MB | knode 4KB | htab 10.8MB |
    //     hist 22KB | offs 22KB | perm 256KB
    const size_t gbytes = (size_t)kGridElems * 8 * sizeof(_Float16);  // 1 MB
    const size_t ebytes = (size_t)nev * 8 * sizeof(float);            // 2 MB
    const size_t kbytes = 4096;
    const size_t hbytes = (size_t)NIP * NKF * 256 * 8;                // 10.8 MB
    const size_t histB  = (size_t)NBUCK_PAD * 4;
    const size_t permB  = (size_t)nev * 4;
    const size_t need = 2 * gbytes + ebytes + kbytes + hbytes + 2 * histB + permB;

    if (ws_size >= need && nev == kGridElems) {
        char* base = (char*)d_ws;
        _Float16* wpdf  = (_Float16*)base;
        _Float16* wff   = (_Float16*)(base + gbytes);
        float*    evc   = (float*)(base + 2 * gbytes);
        float*    knode = (float*)(base + 2 * gbytes + ebytes);
        _Float16* htab  = (_Float16*)(base + 2 * gbytes + ebytes + kbytes);
        int*      hist  = (int*)(base + 2 * gbytes + ebytes + kbytes + hbytes);
        int*      offs  = (int*)((char*)hist + histB);
        int*      perm  = (int*)((char*)offs + histB);

        zero_hist<<<1, 256, 0, stream>>>(hist);
        prep_all<<<kGridElems / 256, 256, 0, stream>>>(
            pdfg, ffg, events, ogx, ogw, fnp, wpdf, wff, evc, knode, hist);
        build_htab<<<dim3(NKF, NIP), 256, 0, stream>>>(wpdf, wff, htab);
        scan_hist<<<1, 256, 0, stream>>>(hist, offs);
        scatter_perm<<<nev / 256, 256, 0, stream>>>(evc, offs, perm);
        sidis_fwd8<<<nev / 4, 256, 0, stream>>>(evc, htab, knode, perm, out);
    } else {
        sidis_fwd_direct<<<nev / 4, 256, 0, stream>>>(events, pdfg, ffg,
                                                      ogx, ogw, fnp, out);
    }
}